// Round 10
// baseline (749.977 us; speedup 1.0000x reference)
//
#include <hip/hip_runtime.h>
#include <hip/hip_bf16.h>

// MoE top-2 of 8: B=1024 tokens, M=10000, H=512.
// R10: R9 (W pre-transposed into per-K-step contiguous tile layout) with the
// global_load_lds source-address fix: the global source must be PER-LANE
// (bs_ + lane*8); the LDS dest is wave-uniform base + lane*16B.

#define B_TOK 1024
#define M_DIM 10000
#define E_NUM 8
#define H_DIM 512
#define NSTEP 313   // ceil(10000/32)
#define SPAD1 316   // padded step count per (e,nt) in WbT1 (79*4)

typedef __attribute__((ext_vector_type(4))) float fx4;
typedef __attribute__((ext_vector_type(8))) short sx8;
typedef __attribute__((ext_vector_type(4))) short sx4;

__device__ __forceinline__ short f2bf(float f) {
  union { __hip_bfloat16 h; short s; } u;
  u.h = __float2bfloat16(f);
  return u.s;
}

__device__ __forceinline__ sx8 pack8(fx4 a, fx4 b) {
  sx8 r;
  r[0] = f2bf(a[0]); r[1] = f2bf(a[1]); r[2] = f2bf(a[2]); r[3] = f2bf(a[3]);
  r[4] = f2bf(b[0]); r[5] = f2bf(b[1]); r[6] = f2bf(b[2]); r[7] = f2bf(b[3]);
  return r;
}

__device__ __forceinline__ void gload16(const short* g, short* l) {
  __builtin_amdgcn_global_load_lds(
      (const __attribute__((address_space(1))) void*)g,
      (__attribute__((address_space(3))) void*)l, 16, 0, 0);
}

__global__ void k_zero(int* cnt, int* cnt2, int* zpad) {
  if (threadIdx.x < E_NUM) cnt[threadIdx.x] = 0;
  if (threadIdx.x < 2 * E_NUM) cnt2[threadIdx.x] = 0;
  if (threadIdx.x < 16) zpad[threadIdx.x] = 0;
}

// Router: f64-accumulated logits, top-2, softmax; fused x->bf16.
__global__ __launch_bounds__(256) void k_router(
    const float* __restrict__ x, const float* __restrict__ Wr,
    int* __restrict__ cnt, int* __restrict__ cnt2,
    int* __restrict__ tokAll, int* __restrict__ qlist2, float* __restrict__ wlist2,
    short* __restrict__ xb)
{
  int b = blockIdx.x, t = threadIdx.x;
  const float* xr = x + (size_t)b * M_DIM;
  short* xbr = xb + (size_t)b * M_DIM;
  double acc[E_NUM];
#pragma unroll
  for (int e = 0; e < E_NUM; e++) acc[e] = 0.0;
  for (int m = t; m < M_DIM; m += 256) {
    float xv = xr[m];
    xbr[m] = f2bf(xv);
#pragma unroll
    for (int e = 0; e < E_NUM; e++)
      acc[e] += (double)xv * (double)Wr[e * M_DIM + m];
  }
#pragma unroll
  for (int e = 0; e < E_NUM; e++) {
#pragma unroll
    for (int off = 32; off > 0; off >>= 1)
      acc[e] += __shfl_xor(acc[e], off);
  }
  __shared__ double part[4][E_NUM];
  int wave = t >> 6;
  if ((t & 63) == 0) {
    for (int e = 0; e < E_NUM; e++) part[wave][e] = acc[e];
  }
  __syncthreads();
  if (t == 0) {
    double lg[E_NUM];
    for (int e = 0; e < E_NUM; e++)
      lg[e] = part[0][e] + part[1][e] + part[2][e] + part[3][e];
    int i0 = 0;
    for (int e = 1; e < E_NUM; e++) if (lg[e] > lg[i0]) i0 = e;
    int i1 = (i0 == 0) ? 1 : 0;
    for (int e = 0; e < E_NUM; e++) if (e != i0 && lg[e] > lg[i1]) i1 = e;
    double ex = exp(lg[i1] - lg[i0]);
    float p0 = (float)(1.0 / (1.0 + ex));
    float p1 = (float)(ex / (1.0 + ex));
    int q0 = atomicAdd(&cnt[i0], 1);
    tokAll[i0 * B_TOK + q0] = b;
    int j0 = atomicAdd(&cnt2[i0 * 2 + 0], 1);
    qlist2[(i0 * 2 + 0) * B_TOK + j0] = q0;
    wlist2[(i0 * 2 + 0) * B_TOK + j0] = p0;
    int q1 = atomicAdd(&cnt[i1], 1);
    tokAll[i1 * B_TOK + q1] = b;
    int j1 = atomicAdd(&cnt2[i1 * 2 + 1], 1);
    qlist2[(i1 * 2 + 1) * B_TOK + j1] = q1;
    wlist2[(i1 * 2 + 1) * B_TOK + j1] = p1;
  }
}

// W1 f32 -> WbT1 tiled bf16: [(e*4+nt)][s][128 rows][32 cols], s padded to 316,
// tail cols zero. LDS transpose: coalesced read + contiguous 8KB step images.
__global__ __launch_bounds__(256) void k_cvt1T(
    const float* __restrict__ W1, short* __restrict__ WbT)
{
  int e = blockIdx.z, nt = blockIdx.y, sc = blockIdx.x;  // sc < 79
  __shared__ short tile[128][136];
  int t = threadIdx.x;
  int row = t >> 1, ch = (t & 1) * 64;
  const float* src = W1 + ((size_t)e * H_DIM + nt * 128 + row) * M_DIM;
  int c0 = sc * 128 + ch;
  if (c0 + 64 <= M_DIM) {
#pragma unroll
    for (int j = 0; j < 8; j++) {
      fx4 a = *(const fx4*)(src + c0 + j * 8);
      fx4 b = *(const fx4*)(src + c0 + j * 8 + 4);
      *(sx8*)&tile[row][ch + j * 8] = pack8(a, b);
    }
  } else {
    for (int j = 0; j < 64; j++) {
      int c = c0 + j;
      tile[row][ch + j] = (c < M_DIM) ? f2bf(src[c]) : (short)0;
    }
  }
  __syncthreads();
  size_t base = ((size_t)(e * 4 + nt) * SPAD1 + sc * 4) * 4096;
  int r = t >> 1, c0w = (t & 1) * 16;
#pragma unroll
  for (int sp = 0; sp < 4; sp++) {
    sx8 v0 = *(sx8*)&tile[r][sp * 32 + c0w];
    sx8 v1 = *(sx8*)&tile[r][sp * 32 + c0w + 8];
    short* dst = WbT + base + (size_t)sp * 4096 + t * 16;
    *(sx8*)(dst) = v0;
    *(sx8*)(dst + 8) = v1;
  }
}

// W2 f32 -> WbT2 tiled bf16: [(e*79+mt)][s=16][128 rows][32 cols], tail M rows zero.
__global__ __launch_bounds__(256) void k_cvt2T(
    const float* __restrict__ W2, short* __restrict__ WbT)
{
  int e = blockIdx.z, mt = blockIdx.y, sc = blockIdx.x;  // sc < 4
  __shared__ short tile[128][136];
  int t = threadIdx.x;
  int row = t >> 1, ch = (t & 1) * 64;
  int grow = mt * 128 + row;
  int c0 = sc * 128 + ch;
  if (grow < M_DIM) {
    const float* src = W2 + ((size_t)e * M_DIM + grow) * H_DIM;
#pragma unroll
    for (int j = 0; j < 8; j++) {
      fx4 a = *(const fx4*)(src + c0 + j * 8);
      fx4 b = *(const fx4*)(src + c0 + j * 8 + 4);
      *(sx8*)&tile[row][ch + j * 8] = pack8(a, b);
    }
  } else {
    sx8 z = {0, 0, 0, 0, 0, 0, 0, 0};
#pragma unroll
    for (int j = 0; j < 8; j++) *(sx8*)&tile[row][ch + j * 8] = z;
  }
  __syncthreads();
  size_t base = ((size_t)(e * 79 + mt) * 16 + sc * 4) * 4096;
  int r = t >> 1, c0w = (t & 1) * 16;
#pragma unroll
  for (int sp = 0; sp < 4; sp++) {
    sx8 v0 = *(sx8*)&tile[r][sp * 32 + c0w];
    sx8 v1 = *(sx8*)&tile[r][sp * 32 + c0w + 8];
    short* dst = WbT + base + (size_t)sp * 4096 + t * 16;
    *(sx8*)(dst) = v0;
    *(sx8*)(dst + 8) = v1;
  }
}

// Fragment reads + 16 MFMAs from 2-buffer LDS.
#define M_MFMA2(cb)                                                         \
  do {                                                                      \
    sx8 af[4], bfr[4];                                                      \
    _Pragma("unroll")                                                       \
    for (int m_ = 0; m_ < 4; m_++)                                          \
      af[m_] = *(const sx8*)(LA[cb] + (wr * 64 + m_ * 16 + lrow) * 32 + khalf * 8); \
    _Pragma("unroll")                                                       \
    for (int n_ = 0; n_ < 4; n_++)                                          \
      bfr[n_] = *(const sx8*)(LB[cb] + (wc * 64 + n_ * 16 + lrow) * 32 + khalf * 8); \
    _Pragma("unroll")                                                       \
    for (int m_ = 0; m_ < 4; m_++)                                          \
      _Pragma("unroll")                                                     \
      for (int n_ = 0; n_ < 4; n_++)                                        \
        acc[m_][n_] = __builtin_amdgcn_mfma_f32_16x16x32_bf16(af[m_], bfr[n_], acc[m_][n_], 0, 0, 0); \
  } while (0)

// GEMM1 split-K: 128 tokens x 128 H, 4 waves; B from tiled WbT1 (contiguous).
__global__ __launch_bounds__(256) void k_mlp1g(
    const short* __restrict__ xb, const short* __restrict__ WbT,
    const int* __restrict__ cnt, const int* __restrict__ tokAll,
    float* __restrict__ partials, const short* __restrict__ zpad, int CH)
{
  int e = blockIdx.z;
  int tt = blockIdx.y >> 2, nt = blockIdx.y & 3;
  int kc = blockIdx.x;

  __shared__ int sh_ne, sh_eoff;
  __shared__ __align__(16) short LA[2][4096];
  __shared__ __align__(16) short LB[2][4096];
  __shared__ int toks[128];

  int t = threadIdx.x;
  if (t == 0) {
    int off = 0;
    for (int k = 0; k < e; k++) off += cnt[k];
    sh_eoff = off; sh_ne = cnt[e];
  }
  __syncthreads();
  int ne = sh_ne, eoff = sh_eoff, row0 = tt * 128;
  if (row0 >= ne) return;
  int nvalid = min(128, ne - row0);
  if (t < 128) toks[t] = tokAll[e * B_TOK + row0 + min(t, nvalid - 1)];
  __syncthreads();

  int lane = t & 63, wave = t >> 6;
  // A staging: per-lane source rows; wave covers rows [wave*32, +32)
  int srA = wave * 32 + (lane >> 2);
  int scol = (lane & 3) * 8;
  const short* ap0 = xb + (size_t)toks[srA] * M_DIM + scol;
  const short* ap1 = xb + (size_t)toks[srA + 16] * M_DIM + scol;
  int ldA0 = (wave * 32) * 32, ldA1 = (wave * 32 + 16) * 32;
  // B staging: contiguous step image; PER-LANE source = base + bo + lane*8
  const short* bbase = WbT + ((size_t)(e * 4 + nt) * SPAD1) * 4096;
  int bo = wave * 1024;
  int blane = bo + lane * 8;

  int wr = wave >> 1, wc = wave & 1;
  int lrow = lane & 15, khalf = lane >> 4;

  fx4 z4 = {0.f, 0.f, 0.f, 0.f};
  fx4 acc[4][4];
#pragma unroll
  for (int m = 0; m < 4; m++)
#pragma unroll
    for (int n = 0; n < 4; n++) acc[m][n] = z4;

  int s0 = kc * CH, s1 = min(s0 + CH, NSTEP);

#define STAGE1(buf, sN)                                        \
  do {                                                         \
    int ko_ = (sN) * 32;                                       \
    bool ok_ = (ko_ + scol + 8 <= M_DIM);                      \
    gload16(ok_ ? (ap0 + ko_) : zpad, LA[buf] + ldA0);         \
    gload16(ok_ ? (ap1 + ko_) : zpad, LA[buf] + ldA1);         \
    const short* bs_ = bbase + (size_t)(sN) * 4096 + blane;    \
    gload16(bs_, LB[buf] + bo);                                \
    gload16(bs_ + 512, LB[buf] + bo + 512);                    \
  } while (0)

  STAGE1(0, s0);
  __syncthreads();

  int c = 0;
  for (int s = s0; s < s1; s++) {
    if (s + 1 < s1) STAGE1(c ^ 1, s + 1);
    M_MFMA2(c);
    __syncthreads();
    c ^= 1;
  }

#pragma unroll
  for (int m = 0; m < 4; m++)
#pragma unroll
    for (int n = 0; n < 4; n++) {
      int colg = nt * 128 + wc * 64 + n * 16 + lrow;
#pragma unroll
      for (int r = 0; r < 4; r++) {
        int rl = wr * 64 + m * 16 + khalf * 4 + r;
        if (rl < nvalid) {
          int grow = eoff + row0 + rl;
          partials[((size_t)kc * 2048 + grow) * H_DIM + colg] = acc[m][n][r];
        }
      }
    }
#undef STAGE1
}

// Reduce split-K partials + bias + relu -> bf16 hbuf.
__global__ __launch_bounds__(256) void k_hreduce(
    const float* __restrict__ partials, const float* __restrict__ b1,
    const int* __restrict__ cnt, short* __restrict__ hbuf, int KC)
{
  __shared__ int sc[E_NUM];
  int t = threadIdx.x;
  if (t < E_NUM) sc[t] = cnt[t];
  __syncthreads();
  int i = (blockIdx.x * 256 + t) * 4;
  int slot = i >> 9;
  int e = 0, off = 0;
  for (int k = 0; k < E_NUM - 1; k++) {
    if (slot >= off + sc[k]) { off += sc[k]; e++; } else break;
  }
  fx4 v = *(const fx4*)(partials + i);
  for (int kc = 1; kc < KC; kc++)
    v += *(const fx4*)(partials + (size_t)kc * 2048 * H_DIM + i);
  fx4 bv = *(const fx4*)(b1 + e * H_DIM + (i & (H_DIM - 1)));
  sx4 o;
#pragma unroll
  for (int j = 0; j < 4; j++) o[j] = f2bf(fmaxf(v[j] + bv[j], 0.f));
  *(sx4*)(hbuf + i) = o;
}

// GEMM2 pass (ord=0 overwrite, ord=1 accumulate). 128x128 tile, K=512;
// B from tiled WbT2 (contiguous 8KB per step).
__global__ __launch_bounds__(256) void k_mlp2g(
    const short* __restrict__ hbuf, const short* __restrict__ WbT,
    const float* __restrict__ b2, const int* __restrict__ cnt,
    const int* __restrict__ cnt2, const int* __restrict__ tokAll,
    const int* __restrict__ qlist2, const float* __restrict__ wlist2,
    float* __restrict__ out, int ord)
{
  int e = blockIdx.z, mt = blockIdx.y, tt = blockIdx.x;

  __shared__ int sh_ne2, sh_eoff;
  __shared__ __align__(16) short LA[2][4096];
  __shared__ __align__(16) short LB[2][4096];
  __shared__ int sl[128];
  __shared__ int tok2[128];
  __shared__ float wts[128];

  int t = threadIdx.x;
  if (t == 0) {
    int off = 0;
    for (int k = 0; k < e; k++) off += cnt[k];
    sh_eoff = off; sh_ne2 = cnt2[e * 2 + ord];
  }
  __syncthreads();
  int ne2 = sh_ne2, eoff = sh_eoff, row0 = tt * 128;
  if (row0 >= ne2) return;
  int nvalid = min(128, ne2 - row0);

  if (t < 128) {
    int j = row0 + min(t, nvalid - 1);
    int q = qlist2[(e * 2 + ord) * B_TOK + j];
    sl[t] = eoff + q;
    tok2[t] = tokAll[e * B_TOK + q];
    wts[t] = (t < nvalid) ? wlist2[(e * 2 + ord) * B_TOK + j] : 0.f;
  }
  __syncthreads();

  int lane = t & 63, wave = t >> 6;
  int srA = wave * 32 + (lane >> 2);
  int scol = (lane & 3) * 8;
  const short* ap0 = hbuf + (size_t)sl[srA] * H_DIM + scol;
  const short* ap1 = hbuf + (size_t)sl[srA + 16] * H_DIM + scol;
  int ldA0 = (wave * 32) * 32, ldA1 = (wave * 32 + 16) * 32;
  const short* bbase = WbT + ((size_t)(e * 79 + mt) * 16) * 4096;
  int bo = wave * 1024;
  int blane = bo + lane * 8;

  int wr = wave >> 1, wc = wave & 1;
  int lrow = lane & 15, khalf = lane >> 4;

  fx4 z4 = {0.f, 0.f, 0.f, 0.f};
  fx4 acc[4][4];
#pragma unroll
  for (int m = 0; m < 4; m++)
#pragma unroll
    for (int n = 0; n < 4; n++) acc[m][n] = z4;

#define STAGE2(buf, sN)                                        \
  do {                                                         \
    int ko_ = (sN) * 32;                                       \
    gload16(ap0 + ko_, LA[buf] + ldA0);                        \
    gload16(ap1 + ko_, LA[buf] + ldA1);                        \
    const short* bs_ = bbase + (size_t)(sN) * 4096 + blane;    \
    gload16(bs_, LB[buf] + bo);                                \
    gload16(bs_ + 512, LB[buf] + bo + 512);                    \
  } while (0)

  STAGE2(0, 0);
  __syncthreads();

  int c = 0;
  for (int s = 0; s < 16; s++) {
    if (s + 1 < 16) STAGE2(c ^ 1, s + 1);
    M_MFMA2(c);
    __syncthreads();
    c ^= 1;
  }

#pragma unroll
  for (int m = 0; m < 4; m++)
#pragma unroll
    for (int n = 0; n < 4; n++) {
      int colg = mt * 128 + wc * 64 + n * 16 + lrow;
      if (colg < M_DIM) {
        float b2v = b2[(size_t)e * M_DIM + colg];
#pragma unroll
        for (int r = 0; r < 4; r++) {
          int rl = wr * 64 + m * 16 + khalf * 4 + r;
          if (rl < nvalid) {
            float v = wts[rl] * (acc[m][n][r] + b2v);
            float* dst = out + (size_t)tok2[rl] * M_DIM + colg;
            if (ord == 0) *dst = v;
            else *dst += v;
          }
        }
      }
    }
#undef STAGE2
}

extern "C" void kernel_launch(void* const* d_in, const int* in_sizes, int n_in,
                              void* d_out, int out_size, void* d_ws, size_t ws_size,
                              hipStream_t stream) {
  const float* x  = (const float*)d_in[0];
  const float* W1 = (const float*)d_in[1];
  const float* b1 = (const float*)d_in[2];
  const float* W2 = (const float*)d_in[3];
  const float* b2 = (const float*)d_in[4];
  const float* Wr = (const float*)d_in[5];
  float* out = (float*)d_out;

  // KC=8 footprint = 139.2MB; KC=5 = 126.6MB (<= proven 138.2MB budget).
  int KC = (ws_size >= 139200000ULL) ? 8 : 5;
  int CH = (NSTEP + KC - 1) / KC;

  char* p = (char*)d_ws;
  float* partials = (float*)p;        p += (size_t)KC * 2048 * H_DIM * 4;
  short* hbuf     = (short*)p;        p += (size_t)2048 * H_DIM * 2;       // 2MB
  int*   cnt      = (int*)p;          p += 64;
  int*   cnt2     = (int*)p;          p += 64;
  int*   tokAll   = (int*)p;          p += E_NUM * B_TOK * 4;
  int*   qlist2   = (int*)p;          p += 2 * E_NUM * B_TOK * 4;
  float* wlist2   = (float*)p;        p += 2 * E_NUM * B_TOK * 4;
  int*   zpad     = (int*)p;          p += 64;
  short* xb       = (short*)p;        p += (size_t)B_TOK * M_DIM * 2;      // 20.5MB
  short* WbT      = (short*)p;        // 8*4*316*4096*2 = 82.8MB (reused for W2 layout, same size)

  k_zero<<<1, 64, 0, stream>>>(cnt, cnt2, zpad);
  k_router<<<B_TOK, 256, 0, stream>>>(x, Wr, cnt, cnt2, tokAll, qlist2, wlist2, xb);
  k_cvt1T<<<dim3(79, 4, E_NUM), 256, 0, stream>>>(W1, WbT);
  k_mlp1g<<<dim3(KC, 32, E_NUM), 256, 0, stream>>>(xb, WbT, cnt, tokAll, partials,
                                                   (const short*)zpad, CH);
  k_hreduce<<<1024, 256, 0, stream>>>(partials, b1, cnt, hbuf, KC);
  k_cvt2T<<<dim3(4, 79, E_NUM), 256, 0, stream>>>(W2, WbT);
  k_mlp2g<<<dim3(8, 79, E_NUM), 256, 0, stream>>>(hbuf, WbT, b2, cnt, cnt2, tokAll,
                                                  qlist2, wlist2, out, 0);
  k_mlp2g<<<dim3(8, 79, E_NUM), 256, 0, stream>>>(hbuf, WbT, b2, cnt, cnt2, tokAll,
                                                  qlist2, wlist2, out, 1);
}

// Round 11
// 364.149 us; speedup vs baseline: 2.0595x; 2.0595x over previous
//
#include <hip/hip_runtime.h>
#include <hip/hip_bf16.h>

// MoE top-2 of 8: B=1024 tokens, M=10000, H=512.
// R11: R10 + mlp2g grid reorder (mt fastest-varying). R10's grid put the
// only-working tt=0 blocks at id%8==0 -> ALL work on one XCD (32/256 CUs).
// Now working blocks are runs of 79 consecutive ids -> spread over 8 XCDs.

#define B_TOK 1024
#define M_DIM 10000
#define E_NUM 8
#define H_DIM 512
#define NSTEP 313   // ceil(10000/32)
#define SPAD1 316   // padded step count per (e,nt) in WbT1 (79*4)

typedef __attribute__((ext_vector_type(4))) float fx4;
typedef __attribute__((ext_vector_type(8))) short sx8;
typedef __attribute__((ext_vector_type(4))) short sx4;

__device__ __forceinline__ short f2bf(float f) {
  union { __hip_bfloat16 h; short s; } u;
  u.h = __float2bfloat16(f);
  return u.s;
}

__device__ __forceinline__ sx8 pack8(fx4 a, fx4 b) {
  sx8 r;
  r[0] = f2bf(a[0]); r[1] = f2bf(a[1]); r[2] = f2bf(a[2]); r[3] = f2bf(a[3]);
  r[4] = f2bf(b[0]); r[5] = f2bf(b[1]); r[6] = f2bf(b[2]); r[7] = f2bf(b[3]);
  return r;
}

__device__ __forceinline__ void gload16(const short* g, short* l) {
  __builtin_amdgcn_global_load_lds(
      (const __attribute__((address_space(1))) void*)g,
      (__attribute__((address_space(3))) void*)l, 16, 0, 0);
}

__global__ void k_zero(int* cnt, int* cnt2, int* zpad) {
  if (threadIdx.x < E_NUM) cnt[threadIdx.x] = 0;
  if (threadIdx.x < 2 * E_NUM) cnt2[threadIdx.x] = 0;
  if (threadIdx.x < 16) zpad[threadIdx.x] = 0;
}

// Router: f64-accumulated logits, top-2, softmax; fused x->bf16.
__global__ __launch_bounds__(256) void k_router(
    const float* __restrict__ x, const float* __restrict__ Wr,
    int* __restrict__ cnt, int* __restrict__ cnt2,
    int* __restrict__ tokAll, int* __restrict__ qlist2, float* __restrict__ wlist2,
    short* __restrict__ xb)
{
  int b = blockIdx.x, t = threadIdx.x;
  const float* xr = x + (size_t)b * M_DIM;
  short* xbr = xb + (size_t)b * M_DIM;
  double acc[E_NUM];
#pragma unroll
  for (int e = 0; e < E_NUM; e++) acc[e] = 0.0;
  for (int m = t; m < M_DIM; m += 256) {
    float xv = xr[m];
    xbr[m] = f2bf(xv);
#pragma unroll
    for (int e = 0; e < E_NUM; e++)
      acc[e] += (double)xv * (double)Wr[e * M_DIM + m];
  }
#pragma unroll
  for (int e = 0; e < E_NUM; e++) {
#pragma unroll
    for (int off = 32; off > 0; off >>= 1)
      acc[e] += __shfl_xor(acc[e], off);
  }
  __shared__ double part[4][E_NUM];
  int wave = t >> 6;
  if ((t & 63) == 0) {
    for (int e = 0; e < E_NUM; e++) part[wave][e] = acc[e];
  }
  __syncthreads();
  if (t == 0) {
    double lg[E_NUM];
    for (int e = 0; e < E_NUM; e++)
      lg[e] = part[0][e] + part[1][e] + part[2][e] + part[3][e];
    int i0 = 0;
    for (int e = 1; e < E_NUM; e++) if (lg[e] > lg[i0]) i0 = e;
    int i1 = (i0 == 0) ? 1 : 0;
    for (int e = 0; e < E_NUM; e++) if (e != i0 && lg[e] > lg[i1]) i1 = e;
    double ex = exp(lg[i1] - lg[i0]);
    float p0 = (float)(1.0 / (1.0 + ex));
    float p1 = (float)(ex / (1.0 + ex));
    int q0 = atomicAdd(&cnt[i0], 1);
    tokAll[i0 * B_TOK + q0] = b;
    int j0 = atomicAdd(&cnt2[i0 * 2 + 0], 1);
    qlist2[(i0 * 2 + 0) * B_TOK + j0] = q0;
    wlist2[(i0 * 2 + 0) * B_TOK + j0] = p0;
    int q1 = atomicAdd(&cnt[i1], 1);
    tokAll[i1 * B_TOK + q1] = b;
    int j1 = atomicAdd(&cnt2[i1 * 2 + 1], 1);
    qlist2[(i1 * 2 + 1) * B_TOK + j1] = q1;
    wlist2[(i1 * 2 + 1) * B_TOK + j1] = p1;
  }
}

// W1 f32 -> WbT1 tiled bf16: [(e*4+nt)][s][128 rows][32 cols], s padded to 316,
// tail cols zero. LDS transpose: coalesced read + contiguous 8KB step images.
__global__ __launch_bounds__(256) void k_cvt1T(
    const float* __restrict__ W1, short* __restrict__ WbT)
{
  int e = blockIdx.z, nt = blockIdx.y, sc = blockIdx.x;  // sc < 79
  __shared__ short tile[128][136];
  int t = threadIdx.x;
  int row = t >> 1, ch = (t & 1) * 64;
  const float* src = W1 + ((size_t)e * H_DIM + nt * 128 + row) * M_DIM;
  int c0 = sc * 128 + ch;
  if (c0 + 64 <= M_DIM) {
#pragma unroll
    for (int j = 0; j < 8; j++) {
      fx4 a = *(const fx4*)(src + c0 + j * 8);
      fx4 b = *(const fx4*)(src + c0 + j * 8 + 4);
      *(sx8*)&tile[row][ch + j * 8] = pack8(a, b);
    }
  } else {
    for (int j = 0; j < 64; j++) {
      int c = c0 + j;
      tile[row][ch + j] = (c < M_DIM) ? f2bf(src[c]) : (short)0;
    }
  }
  __syncthreads();
  size_t base = ((size_t)(e * 4 + nt) * SPAD1 + sc * 4) * 4096;
  int c0w = (t & 1) * 16;
  int r = t >> 1;
#pragma unroll
  for (int sp = 0; sp < 4; sp++) {
    sx8 v0 = *(sx8*)&tile[r][sp * 32 + c0w];
    sx8 v1 = *(sx8*)&tile[r][sp * 32 + c0w + 8];
    short* dst = WbT + base + (size_t)sp * 4096 + t * 16;
    *(sx8*)(dst) = v0;
    *(sx8*)(dst + 8) = v1;
  }
}

// W2 f32 -> WbT2 tiled bf16: [(e*79+mt)][s=16][128 rows][32 cols], tail M rows zero.
__global__ __launch_bounds__(256) void k_cvt2T(
    const float* __restrict__ W2, short* __restrict__ WbT)
{
  int e = blockIdx.z, mt = blockIdx.y, sc = blockIdx.x;  // sc < 4
  __shared__ short tile[128][136];
  int t = threadIdx.x;
  int row = t >> 1, ch = (t & 1) * 64;
  int grow = mt * 128 + row;
  int c0 = sc * 128 + ch;
  if (grow < M_DIM) {
    const float* src = W2 + ((size_t)e * M_DIM + grow) * H_DIM;
#pragma unroll
    for (int j = 0; j < 8; j++) {
      fx4 a = *(const fx4*)(src + c0 + j * 8);
      fx4 b = *(const fx4*)(src + c0 + j * 8 + 4);
      *(sx8*)&tile[row][ch + j * 8] = pack8(a, b);
    }
  } else {
    sx8 z = {0, 0, 0, 0, 0, 0, 0, 0};
#pragma unroll
    for (int j = 0; j < 8; j++) *(sx8*)&tile[row][ch + j * 8] = z;
  }
  __syncthreads();
  size_t base = ((size_t)(e * 79 + mt) * 16 + sc * 4) * 4096;
  int c0w = (t & 1) * 16;
  int r = t >> 1;
#pragma unroll
  for (int sp = 0; sp < 4; sp++) {
    sx8 v0 = *(sx8*)&tile[r][sp * 32 + c0w];
    sx8 v1 = *(sx8*)&tile[r][sp * 32 + c0w + 8];
    short* dst = WbT + base + (size_t)sp * 4096 + t * 16;
    *(sx8*)(dst) = v0;
    *(sx8*)(dst + 8) = v1;
  }
}

// Fragment reads + 16 MFMAs from 2-buffer LDS.
#define M_MFMA2(cb)                                                         \
  do {                                                                      \
    sx8 af[4], bfr[4];                                                      \
    _Pragma("unroll")                                                       \
    for (int m_ = 0; m_ < 4; m_++)                                          \
      af[m_] = *(const sx8*)(LA[cb] + (wr * 64 + m_ * 16 + lrow) * 32 + khalf * 8); \
    _Pragma("unroll")                                                       \
    for (int n_ = 0; n_ < 4; n_++)                                          \
      bfr[n_] = *(const sx8*)(LB[cb] + (wc * 64 + n_ * 16 + lrow) * 32 + khalf * 8); \
    __builtin_amdgcn_s_setprio(1);                                          \
    _Pragma("unroll")                                                       \
    for (int m_ = 0; m_ < 4; m_++)                                          \
      _Pragma("unroll")                                                     \
      for (int n_ = 0; n_ < 4; n_++)                                        \
        acc[m_][n_] = __builtin_amdgcn_mfma_f32_16x16x32_bf16(af[m_], bfr[n_], acc[m_][n_], 0, 0, 0); \
    __builtin_amdgcn_s_setprio(0);                                          \
  } while (0)

// GEMM1 split-K: 128 tokens x 128 H, 4 waves; B from tiled WbT1 (contiguous).
__global__ __launch_bounds__(256) void k_mlp1g(
    const short* __restrict__ xb, const short* __restrict__ WbT,
    const int* __restrict__ cnt, const int* __restrict__ tokAll,
    float* __restrict__ partials, const short* __restrict__ zpad, int CH)
{
  int e = blockIdx.z;
  int tt = blockIdx.y >> 2, nt = blockIdx.y & 3;
  int kc = blockIdx.x;

  __shared__ int sh_ne, sh_eoff;
  __shared__ __align__(16) short LA[2][4096];
  __shared__ __align__(16) short LB[2][4096];
  __shared__ int toks[128];

  int t = threadIdx.x;
  if (t == 0) {
    int off = 0;
    for (int k = 0; k < e; k++) off += cnt[k];
    sh_eoff = off; sh_ne = cnt[e];
  }
  __syncthreads();
  int ne = sh_ne, eoff = sh_eoff, row0 = tt * 128;
  if (row0 >= ne) return;
  int nvalid = min(128, ne - row0);
  if (t < 128) toks[t] = tokAll[e * B_TOK + row0 + min(t, nvalid - 1)];
  __syncthreads();

  int lane = t & 63, wave = t >> 6;
  int srA = wave * 32 + (lane >> 2);
  int scol = (lane & 3) * 8;
  const short* ap0 = xb + (size_t)toks[srA] * M_DIM + scol;
  const short* ap1 = xb + (size_t)toks[srA + 16] * M_DIM + scol;
  int ldA0 = (wave * 32) * 32, ldA1 = (wave * 32 + 16) * 32;
  const short* bbase = WbT + ((size_t)(e * 4 + nt) * SPAD1) * 4096;
  int bo = wave * 1024;
  int blane = bo + lane * 8;

  int wr = wave >> 1, wc = wave & 1;
  int lrow = lane & 15, khalf = lane >> 4;

  fx4 z4 = {0.f, 0.f, 0.f, 0.f};
  fx4 acc[4][4];
#pragma unroll
  for (int m = 0; m < 4; m++)
#pragma unroll
    for (int n = 0; n < 4; n++) acc[m][n] = z4;

  int s0 = kc * CH, s1 = min(s0 + CH, NSTEP);

#define STAGE1(buf, sN)                                        \
  do {                                                         \
    int ko_ = (sN) * 32;                                       \
    bool ok_ = (ko_ + scol + 8 <= M_DIM);                      \
    gload16(ok_ ? (ap0 + ko_) : zpad, LA[buf] + ldA0);         \
    gload16(ok_ ? (ap1 + ko_) : zpad, LA[buf] + ldA1);         \
    const short* bs_ = bbase + (size_t)(sN) * 4096 + blane;    \
    gload16(bs_, LB[buf] + bo);                                \
    gload16(bs_ + 512, LB[buf] + bo + 512);                    \
  } while (0)

  STAGE1(0, s0);
  __syncthreads();

  int c = 0;
  for (int s = s0; s < s1; s++) {
    if (s + 1 < s1) STAGE1(c ^ 1, s + 1);
    M_MFMA2(c);
    __syncthreads();
    c ^= 1;
  }

#pragma unroll
  for (int m = 0; m < 4; m++)
#pragma unroll
    for (int n = 0; n < 4; n++) {
      int colg = nt * 128 + wc * 64 + n * 16 + lrow;
#pragma unroll
      for (int r = 0; r < 4; r++) {
        int rl = wr * 64 + m * 16 + khalf * 4 + r;
        if (rl < nvalid) {
          int grow = eoff + row0 + rl;
          partials[((size_t)kc * 2048 + grow) * H_DIM + colg] = acc[m][n][r];
        }
      }
    }
#undef STAGE1
}

// Reduce split-K partials + bias + relu -> bf16 hbuf.
__global__ __launch_bounds__(256) void k_hreduce(
    const float* __restrict__ partials, const float* __restrict__ b1,
    const int* __restrict__ cnt, short* __restrict__ hbuf, int KC)
{
  __shared__ int sc[E_NUM];
  int t = threadIdx.x;
  if (t < E_NUM) sc[t] = cnt[t];
  __syncthreads();
  int i = (blockIdx.x * 256 + t) * 4;
  int slot = i >> 9;
  int e = 0, off = 0;
  for (int k = 0; k < E_NUM - 1; k++) {
    if (slot >= off + sc[k]) { off += sc[k]; e++; } else break;
  }
  fx4 v = *(const fx4*)(partials + i);
  for (int kc = 1; kc < KC; kc++)
    v += *(const fx4*)(partials + (size_t)kc * 2048 * H_DIM + i);
  fx4 bv = *(const fx4*)(b1 + e * H_DIM + (i & (H_DIM - 1)));
  sx4 o;
#pragma unroll
  for (int j = 0; j < 4; j++) o[j] = f2bf(fmaxf(v[j] + bv[j], 0.f));
  *(sx4*)(hbuf + i) = o;
}

// GEMM2 pass (ord=0 overwrite, ord=1 accumulate). 128x128 tile, K=512;
// B from tiled WbT2. GRID: mt = blockIdx.x (all working), tt = blockIdx.y.
__global__ __launch_bounds__(256) void k_mlp2g(
    const short* __restrict__ hbuf, const short* __restrict__ WbT,
    const float* __restrict__ b2, const int* __restrict__ cnt,
    const int* __restrict__ cnt2, const int* __restrict__ tokAll,
    const int* __restrict__ qlist2, const float* __restrict__ wlist2,
    float* __restrict__ out, int ord)
{
  int e = blockIdx.z, mt = blockIdx.x, tt = blockIdx.y;

  __shared__ int sh_ne2, sh_eoff;
  __shared__ __align__(16) short LA[2][4096];
  __shared__ __align__(16) short LB[2][4096];
  __shared__ int sl[128];
  __shared__ int tok2[128];
  __shared__ float wts[128];

  int t = threadIdx.x;
  if (t == 0) {
    int off = 0;
    for (int k = 0; k < e; k++) off += cnt[k];
    sh_eoff = off; sh_ne2 = cnt2[e * 2 + ord];
  }
  __syncthreads();
  int ne2 = sh_ne2, eoff = sh_eoff, row0 = tt * 128;
  if (row0 >= ne2) return;
  int nvalid = min(128, ne2 - row0);

  if (t < 128) {
    int j = row0 + min(t, nvalid - 1);
    int q = qlist2[(e * 2 + ord) * B_TOK + j];
    sl[t] = eoff + q;
    tok2[t] = tokAll[e * B_TOK + q];
    wts[t] = (t < nvalid) ? wlist2[(e * 2 + ord) * B_TOK + j] : 0.f;
  }
  __syncthreads();

  int lane = t & 63, wave = t >> 6;
  int srA = wave * 32 + (lane >> 2);
  int scol = (lane & 3) * 8;
  const short* ap0 = hbuf + (size_t)sl[srA] * H_DIM + scol;
  const short* ap1 = hbuf + (size_t)sl[srA + 16] * H_DIM + scol;
  int ldA0 = (wave * 32) * 32, ldA1 = (wave * 32 + 16) * 32;
  const short* bbase = WbT + ((size_t)(e * 79 + mt) * 16) * 4096;
  int bo = wave * 1024;
  int blane = bo + lane * 8;

  int wr = wave >> 1, wc = wave & 1;
  int lrow = lane & 15, khalf = lane >> 4;

  fx4 z4 = {0.f, 0.f, 0.f, 0.f};
  fx4 acc[4][4];
#pragma unroll
  for (int m = 0; m < 4; m++)
#pragma unroll
    for (int n = 0; n < 4; n++) acc[m][n] = z4;

#define STAGE2(buf, sN)                                        \
  do {                                                         \
    int ko_ = (sN) * 32;                                       \
    gload16(ap0 + ko_, LA[buf] + ldA0);                        \
    gload16(ap1 + ko_, LA[buf] + ldA1);                        \
    const short* bs_ = bbase + (size_t)(sN) * 4096 + blane;    \
    gload16(bs_, LB[buf] + bo);                                \
    gload16(bs_ + 512, LB[buf] + bo + 512);                    \
  } while (0)

  STAGE2(0, 0);
  __syncthreads();

  int c = 0;
  for (int s = 0; s < 16; s++) {
    if (s + 1 < 16) STAGE2(c ^ 1, s + 1);
    M_MFMA2(c);
    __syncthreads();
    c ^= 1;
  }

#pragma unroll
  for (int m = 0; m < 4; m++)
#pragma unroll
    for (int n = 0; n < 4; n++) {
      int colg = mt * 128 + wc * 64 + n * 16 + lrow;
      if (colg < M_DIM) {
        float b2v = b2[(size_t)e * M_DIM + colg];
#pragma unroll
        for (int r = 0; r < 4; r++) {
          int rl = wr * 64 + m * 16 + khalf * 4 + r;
          if (rl < nvalid) {
            float v = wts[rl] * (acc[m][n][r] + b2v);
            float* dst = out + (size_t)tok2[rl] * M_DIM + colg;
            if (ord == 0) *dst = v;
            else *dst += v;
          }
        }
      }
    }
#undef STAGE2
}

extern "C" void kernel_launch(void* const* d_in, const int* in_sizes, int n_in,
                              void* d_out, int out_size, void* d_ws, size_t ws_size,
                              hipStream_t stream) {
  const float* x  = (const float*)d_in[0];
  const float* W1 = (const float*)d_in[1];
  const float* b1 = (const float*)d_in[2];
  const float* W2 = (const float*)d_in[3];
  const float* b2 = (const float*)d_in[4];
  const float* Wr = (const float*)d_in[5];
  float* out = (float*)d_out;

  // KC=8 footprint = 139.2MB; KC=5 = 126.6MB (<= proven 138.2MB budget).
  int KC = (ws_size >= 139200000ULL) ? 8 : 5;
  int CH = (NSTEP + KC - 1) / KC;

  char* p = (char*)d_ws;
  float* partials = (float*)p;        p += (size_t)KC * 2048 * H_DIM * 4;
  short* hbuf     = (short*)p;        p += (size_t)2048 * H_DIM * 2;       // 2MB
  int*   cnt      = (int*)p;          p += 64;
  int*   cnt2     = (int*)p;          p += 64;
  int*   tokAll   = (int*)p;          p += E_NUM * B_TOK * 4;
  int*   qlist2   = (int*)p;          p += 2 * E_NUM * B_TOK * 4;
  float* wlist2   = (float*)p;        p += 2 * E_NUM * B_TOK * 4;
  int*   zpad     = (int*)p;          p += 64;
  short* xb       = (short*)p;        p += (size_t)B_TOK * M_DIM * 2;      // 20.5MB
  short* WbT      = (short*)p;        // 82.8MB (W1 layout; reused for W2 layout)

  k_zero<<<1, 64, 0, stream>>>(cnt, cnt2, zpad);
  k_router<<<B_TOK, 256, 0, stream>>>(x, Wr, cnt, cnt2, tokAll, qlist2, wlist2, xb);
  k_cvt1T<<<dim3(79, 4, E_NUM), 256, 0, stream>>>(W1, WbT);
  k_mlp1g<<<dim3(KC, 32, E_NUM), 256, 0, stream>>>(xb, WbT, cnt, tokAll, partials,
                                                   (const short*)zpad, CH);
  k_hreduce<<<1024, 256, 0, stream>>>(partials, b1, cnt, hbuf, KC);
  k_cvt2T<<<dim3(4, 79, E_NUM), 256, 0, stream>>>(W2, WbT);
  k_mlp2g<<<dim3(79, 8, E_NUM), 256, 0, stream>>>(hbuf, WbT, b2, cnt, cnt2, tokAll,
                                                  qlist2, wlist2, out, 0);
  k_mlp2g<<<dim3(79, 8, E_NUM), 256, 0, stream>>>(hbuf, WbT, b2, cnt, cnt2, tokAll,
                                                  qlist2, wlist2, out, 1);
}